// Round 1
// baseline (628.768 us; speedup 1.0000x reference)
//
#include <hip/hip_runtime.h>
#include <math.h>

#define Hh 128
#define Ww 128
#define Dd 256
#define Bb 4
#define HW (Hh*Ww)        // 16384
#define NPIX (Bb*HW)      // 65536

// ---------- wave (64-lane) butterfly reductions ----------
__device__ __forceinline__ float wsum(float v) {
#pragma unroll
    for (int o = 32; o; o >>= 1) v += __shfl_xor(v, o, 64);
    return v;
}
__device__ __forceinline__ float wmax(float v) {
#pragma unroll
    for (int o = 32; o; o >>= 1) v = fmaxf(v, __shfl_xor(v, o, 64));
    return v;
}

// ---------- K1: L2-normalize vis tokens -> kn [B,H,W,D] (channel-last) ----------
__global__ __launch_bounds__(256) void norm_vis(const float* __restrict__ vis,
                                                float* __restrict__ kn) {
    int wid = threadIdx.x >> 6, lane = threadIdx.x & 63;
    int pix = blockIdx.x * 4 + wid;
    const float4 v = *(const float4*)(vis + (size_t)pix * Dd + lane * 4);
    float ss = wsum(v.x * v.x + v.y * v.y + v.z * v.z + v.w * v.w);
    float inv = 1.0f / fmaxf(sqrtf(ss), 1e-12f);
    float4 o;
    o.x = v.x * inv; o.y = v.y * inv; o.z = v.z * inv; o.w = v.w * inv;
    *(float4*)(kn + (size_t)pix * Dd + lane * 4) = o;
}

// ---------- K2: bilinear-upsample rubin 64x64 -> 128x128 + L2 norm -> qn ----------
__global__ __launch_bounds__(256) void interp_norm_q(const float* __restrict__ rub,
                                                     float* __restrict__ qn) {
    int wid = threadIdx.x >> 6, lane = threadIdx.x & 63;
    int pix = blockIdx.x * 4 + wid;
    int b = pix >> 14; int yx = pix & 16383; int y = yx >> 7; int x = yx & 127;
    // half-pixel bilinear, scale 0.5: src = (i+0.5)*0.5 - 0.5
    float sy = 0.5f * y - 0.25f;
    float sx = 0.5f * x - 0.25f;
    int y0 = (int)floorf(sy); float fy = sy - (float)y0;
    int x0 = (int)floorf(sx); float fx = sx - (float)x0;
    int y0c = max(y0, 0), y1c = min(y0 + 1, 63);
    int x0c = max(x0, 0), x1c = min(x0 + 1, 63);
    const float* base = rub + (size_t)b * 4096 * Dd;
    const float4 v00 = *(const float4*)(base + (size_t)(y0c * 64 + x0c) * Dd + lane * 4);
    const float4 v01 = *(const float4*)(base + (size_t)(y0c * 64 + x1c) * Dd + lane * 4);
    const float4 v10 = *(const float4*)(base + (size_t)(y1c * 64 + x0c) * Dd + lane * 4);
    const float4 v11 = *(const float4*)(base + (size_t)(y1c * 64 + x1c) * Dd + lane * 4);
    float w00 = (1.f - fy) * (1.f - fx), w01 = (1.f - fy) * fx;
    float w10 = fy * (1.f - fx), w11 = fy * fx;
    float4 v;
    v.x = w00 * v00.x + w01 * v01.x + w10 * v10.x + w11 * v11.x;
    v.y = w00 * v00.y + w01 * v01.y + w10 * v10.y + w11 * v11.y;
    v.z = w00 * v00.z + w01 * v01.z + w10 * v10.z + w11 * v11.z;
    v.w = w00 * v00.w + w01 * v01.w + w10 * v10.w + w11 * v11.w;
    float ss = wsum(v.x * v.x + v.y * v.y + v.z * v.z + v.w * v.w);
    float inv = 1.0f / fmaxf(sqrtf(ss), 1e-12f);
    float4 o;
    o.x = v.x * inv; o.y = v.y * inv; o.z = v.z * inv; o.w = v.w * inv;
    *(float4*)(qn + (size_t)pix * Dd + lane * 4) = o;
}

// ---------- K3: 49-ch corr + softmax soft-argmax ----------
// writes xf [B,H,W,52] (ch0=dy, ch1=dx, ch2..50=corr, ch51=conf)
// writes out channels 2(dy),3(dx),4(conf)
__global__ __launch_bounds__(256) void corr_softargmax(const float* __restrict__ qn,
                                                       const float* __restrict__ kn,
                                                       const float* __restrict__ log_temp,
                                                       float* __restrict__ xf,
                                                       float* __restrict__ out) {
    int wid = threadIdx.x >> 6, lane = threadIdx.x & 63;
    int pix = blockIdx.x * 4 + wid;
    int b = pix >> 14; int yx = pix & 16383; int y = yx >> 7; int x = yx & 127;
    const float4 q = *(const float4*)(qn + (size_t)pix * Dd + lane * 4);
    float temp = expf(log_temp[0]);
    float mine = -1e30f;  // this lane's corr value (lane == offset index s)
    for (int s = 0; s < 49; s++) {
        int dy = s / 7 - 3, dx = s % 7 - 3;
        int yy = min(max(y + dy, 0), Hh - 1);
        int xx = min(max(x + dx, 0), Ww - 1);
        const float4 kv = *(const float4*)(kn + ((size_t)(b << 14) + yy * Ww + xx) * Dd + lane * 4);
        float p = q.x * kv.x + q.y * kv.y + q.z * kv.z + q.w * kv.w;
        p = wsum(p);
        if (lane == s) mine = p;
    }
    float cmax = wmax(mine);
    float e = (lane < 49) ? expf((mine - cmax) / temp) : 0.0f;
    float esum = wsum(e);
    float wgt = e / esum;
    float conf = wmax(wgt);
    float cy = (float)(lane / 7 - 3);
    float cx = (float)(lane % 7 - 3);
    float dyv = wsum(wgt * cy);
    float dxv = wsum(wgt * cx);
    float* xp = xf + (size_t)pix * 52;
    if (lane < 49) xp[2 + lane] = mine;
    if (lane == 0) {
        xp[0] = dyv; xp[1] = dxv; xp[51] = conf;
        float* op = out + (size_t)b * 5 * HW + yx;
        op[2 * HW] = dyv;
        op[3 * HW] = dxv;
        op[4 * HW] = conf;
    }
}

// ---------- K0: transpose conv weights [OC,IC,5,5] -> [25,IC,OC] ----------
__global__ __launch_bounds__(256) void prep_weights(const float* __restrict__ w0,
                                                    const float* __restrict__ w1,
                                                    const float* __restrict__ w2,
                                                    float* __restrict__ t0,
                                                    float* __restrict__ t1,
                                                    float* __restrict__ t2) {
    int t = blockIdx.x * 256 + threadIdx.x;
    if (t < 41600) {                      // w0: 32x52x25
        int k = t / (52 * 32); int r = t % (52 * 32); int ic = r / 32, oc = r % 32;
        t0[t] = w0[oc * (52 * 25) + ic * 25 + k];
    } else if (t < 41600 + 25600) {       // w1: 32x32x25
        int u = t - 41600;
        int k = u / 1024; int r = u % 1024; int ic = r / 32, oc = r % 32;
        t1[u] = w1[oc * (32 * 25) + ic * 25 + k];
    } else if (t < 41600 + 25600 + 1600) {// w2: 2x32x25
        int u = t - 67200;
        int k = u / 64; int r = u % 64; int ic = r / 2, oc = r % 2;
        t2[u] = w2[oc * (32 * 25) + ic * 25 + k];
    }
}

__device__ __forceinline__ float gelu_exact(float v) {
    return 0.5f * v * (1.0f + erff(v * 0.70710678118654752f));
}

// ---------- conv 5x5 SAME (zero pad), channel-last in/out, fused GELU ----------
template <int IC, int OCTOT, int OCG, bool GELU>
__global__ __launch_bounds__(256) void conv5x5(const float* __restrict__ in,
                                               const float* __restrict__ wt,
                                               const float* __restrict__ bias,
                                               float* __restrict__ outp) {
    constexpr int NG = OCTOT / OCG;
    int x = blockIdx.x * 16 + threadIdx.x;
    int y = blockIdx.y * 16 + threadIdx.y;
    int b = blockIdx.z / NG;
    int g = blockIdx.z % NG;
    int ocb = g * OCG;
    float acc[OCG];
#pragma unroll
    for (int o = 0; o < OCG; o++) acc[o] = bias[ocb + o];
#pragma unroll
    for (int ky = 0; ky < 5; ky++) {
        int yy = y + ky - 2;
        if ((unsigned)yy >= (unsigned)Hh) continue;
#pragma unroll
        for (int kx = 0; kx < 5; kx++) {
            int xx = x + kx - 2;
            if ((unsigned)xx >= (unsigned)Ww) continue;
            const float* xp = in + (size_t)((b * Hh + yy) * Ww + xx) * IC;
            const float* wp = wt + (ky * 5 + kx) * IC * OCTOT + ocb;
#pragma unroll
            for (int ic4 = 0; ic4 < IC / 4; ic4++) {
                float4 xv = *(const float4*)(xp + ic4 * 4);
                const float* wq = wp + ic4 * 4 * OCTOT;
#pragma unroll
                for (int j = 0; j < 4; j++) {
                    float xs = (j == 0) ? xv.x : (j == 1) ? xv.y : (j == 2) ? xv.z : xv.w;
#pragma unroll
                    for (int o = 0; o < OCG; o++)
                        acc[o] = fmaf(xs, wq[j * OCTOT + o], acc[o]);
                }
            }
        }
    }
    float* op = outp + (size_t)((b * Hh + y) * Ww + x) * OCTOT + ocb;
#pragma unroll
    for (int o = 0; o < OCG; o++) {
        float v = acc[o];
        if (GELU) v = gelu_exact(v);
        op[o] = v;
    }
}

// ---------- conv2 (32->2) + residual add + sky scaling -> out ch0/ch1 ----------
__global__ __launch_bounds__(256) void conv5x5_final(const float* __restrict__ in,
                                                     const float* __restrict__ wt,
                                                     const float* __restrict__ bias,
                                                     const float* __restrict__ xf,
                                                     float* __restrict__ out) {
    int x = blockIdx.x * 16 + threadIdx.x;
    int y = blockIdx.y * 16 + threadIdx.y;
    int b = blockIdx.z;
    float a0 = bias[0], a1 = bias[1];
#pragma unroll
    for (int ky = 0; ky < 5; ky++) {
        int yy = y + ky - 2;
        if ((unsigned)yy >= (unsigned)Hh) continue;
#pragma unroll
        for (int kx = 0; kx < 5; kx++) {
            int xx = x + kx - 2;
            if ((unsigned)xx >= (unsigned)Ww) continue;
            const float* xp = in + (size_t)((b * Hh + yy) * Ww + xx) * 32;
            const float* wp = wt + (ky * 5 + kx) * 32 * 2;
#pragma unroll
            for (int ic4 = 0; ic4 < 8; ic4++) {
                float4 xv = *(const float4*)(xp + ic4 * 4);
#pragma unroll
                for (int j = 0; j < 4; j++) {
                    float xs = (j == 0) ? xv.x : (j == 1) ? xv.y : (j == 2) ? xv.z : xv.w;
                    a0 = fmaf(xs, wp[(ic4 * 4 + j) * 2 + 0], a0);
                    a1 = fmaf(xs, wp[(ic4 * 4 + j) * 2 + 1], a1);
                }
            }
        }
    }
    size_t pix = (size_t)((b * Hh + y) * Ww + x);
    float rdy = xf[pix * 52 + 0];
    float rdx = xf[pix * 52 + 1];
    float r0 = rdy + a0;   // refined dy
    float r1 = rdx + a1;   // refined dx
    // sky_per_token = 2048 * 0.1 / 128 = 1.6 (both axes)
    float* op = out + (size_t)b * 5 * HW + y * Ww + x;
    op[0] = r1 * 1.6f;     // dra
    op[HW] = r0 * 1.6f;    // ddec
}

extern "C" void kernel_launch(void* const* d_in, const int* in_sizes, int n_in,
                              void* d_out, int out_size, void* d_ws, size_t ws_size,
                              hipStream_t stream) {
    const float* rub = (const float*)d_in[0];
    const float* vis = (const float*)d_in[1];
    const float* w0 = (const float*)d_in[2];
    const float* b0 = (const float*)d_in[3];
    const float* w1 = (const float*)d_in[4];
    const float* b1 = (const float*)d_in[5];
    const float* w2 = (const float*)d_in[6];
    const float* b2 = (const float*)d_in[7];
    const float* log_temp = (const float*)d_in[8];
    float* out = (float*)d_out;

    float* ws = (float*)d_ws;
    size_t off = 0;
    float* kn = ws + off; off += (size_t)NPIX * Dd;   // 16.8M floats
    float* qn = ws + off; off += (size_t)NPIX * Dd;   // 16.8M floats
    float* xf = ws + off; off += (size_t)NPIX * 52;   // 3.4M floats
    float* h1 = ws + off; off += (size_t)NPIX * 32;   // 2.1M floats
    float* h2 = ws + off; off += (size_t)NPIX * 32;   // 2.1M floats
    float* t0 = ws + off; off += 41600;
    float* t1 = ws + off; off += 25600;
    float* t2 = ws + off; off += 1600;
    // total ~165 MB

    prep_weights<<<(68800 + 255) / 256, 256, 0, stream>>>(w0, w1, w2, t0, t1, t2);
    norm_vis<<<NPIX / 4, 256, 0, stream>>>(vis, kn);
    interp_norm_q<<<NPIX / 4, 256, 0, stream>>>(rub, qn);
    corr_softargmax<<<NPIX / 4, 256, 0, stream>>>(qn, kn, log_temp, xf, out);

    dim3 blk(16, 16);
    conv5x5<52, 32, 16, true><<<dim3(8, 8, Bb * 2), blk, 0, stream>>>(xf, t0, b0, h1);
    conv5x5<32, 32, 16, true><<<dim3(8, 8, Bb * 2), blk, 0, stream>>>(h1, t1, b1, h2);
    conv5x5_final<<<dim3(8, 8, Bb), blk, 0, stream>>>(h2, t2, b2, xf, out);
}

// Round 2
// 430.891 us; speedup vs baseline: 1.4592x; 1.4592x over previous
//
#include <hip/hip_runtime.h>
#include <math.h>

#define Hh 128
#define Ww 128
#define Dd 256
#define Bb 4
#define HW (Hh*Ww)        // 16384
#define NPIX (Bb*HW)      // 65536

typedef __attribute__((ext_vector_type(8))) short s16x8;   // 8 bf16 (4 VGPRs)
typedef __attribute__((ext_vector_type(4))) float f32x4;

// ---------- wave (64-lane) butterfly reductions ----------
__device__ __forceinline__ float wsum(float v) {
#pragma unroll
    for (int o = 32; o; o >>= 1) v += __shfl_xor(v, o, 64);
    return v;
}

// fp32 -> bf16 RNE
__device__ __forceinline__ unsigned short f2bf(float f) {
    unsigned u = __float_as_uint(f);
    u += 0x7FFF + ((u >> 16) & 1);
    return (unsigned short)(u >> 16);
}

// ---------- K1: L2-normalize vis tokens -> kn [B,H,W,D] bf16 ----------
__global__ __launch_bounds__(256) void norm_vis(const float* __restrict__ vis,
                                                unsigned short* __restrict__ kn) {
    int wid = threadIdx.x >> 6, lane = threadIdx.x & 63;
    int pix = blockIdx.x * 4 + wid;
    const float4 v = *(const float4*)(vis + (size_t)pix * Dd + lane * 4);
    float ss = wsum(v.x * v.x + v.y * v.y + v.z * v.z + v.w * v.w);
    float inv = 1.0f / fmaxf(sqrtf(ss), 1e-12f);
    ushort4 o;
    o.x = f2bf(v.x * inv); o.y = f2bf(v.y * inv);
    o.z = f2bf(v.z * inv); o.w = f2bf(v.w * inv);
    *(ushort4*)(kn + (size_t)pix * Dd + lane * 4) = o;
}

// ---------- K2: bilinear-upsample rubin 64x64 -> 128x128 + L2 norm -> qn bf16 ----------
__global__ __launch_bounds__(256) void interp_norm_q(const float* __restrict__ rub,
                                                     unsigned short* __restrict__ qn) {
    int wid = threadIdx.x >> 6, lane = threadIdx.x & 63;
    int pix = blockIdx.x * 4 + wid;
    int b = pix >> 14; int yx = pix & 16383; int y = yx >> 7; int x = yx & 127;
    float sy = 0.5f * y - 0.25f;
    float sx = 0.5f * x - 0.25f;
    int y0 = (int)floorf(sy); float fy = sy - (float)y0;
    int x0 = (int)floorf(sx); float fx = sx - (float)x0;
    int y0c = max(y0, 0), y1c = min(y0 + 1, 63);
    int x0c = max(x0, 0), x1c = min(x0 + 1, 63);
    const float* base = rub + (size_t)b * 4096 * Dd;
    const float4 v00 = *(const float4*)(base + (size_t)(y0c * 64 + x0c) * Dd + lane * 4);
    const float4 v01 = *(const float4*)(base + (size_t)(y0c * 64 + x1c) * Dd + lane * 4);
    const float4 v10 = *(const float4*)(base + (size_t)(y1c * 64 + x0c) * Dd + lane * 4);
    const float4 v11 = *(const float4*)(base + (size_t)(y1c * 64 + x1c) * Dd + lane * 4);
    float w00 = (1.f - fy) * (1.f - fx), w01 = (1.f - fy) * fx;
    float w10 = fy * (1.f - fx), w11 = fy * fx;
    float4 v;
    v.x = w00 * v00.x + w01 * v01.x + w10 * v10.x + w11 * v11.x;
    v.y = w00 * v00.y + w01 * v01.y + w10 * v10.y + w11 * v11.y;
    v.z = w00 * v00.z + w01 * v01.z + w10 * v10.z + w11 * v11.z;
    v.w = w00 * v00.w + w01 * v01.w + w10 * v10.w + w11 * v11.w;
    float ss = wsum(v.x * v.x + v.y * v.y + v.z * v.z + v.w * v.w);
    float inv = 1.0f / fmaxf(sqrtf(ss), 1e-12f);
    ushort4 o;
    o.x = f2bf(v.x * inv); o.y = f2bf(v.y * inv);
    o.z = f2bf(v.z * inv); o.w = f2bf(v.w * inv);
    *(ushort4*)(qn + (size_t)pix * Dd + lane * 4) = o;
}

// ---------- K3: MFMA corr (16 px row-tile x 154 neighborhood) + softmax ----------
// wave w of block handles tile = blockIdx.x*4+w : 16 pixels (b, y, x0..x0+15)
// C[m=pixel][n=position], positions = 7 rows (y-3..y+3) x 22 cols (x0-3..x0+18)
__global__ __launch_bounds__(256) void corr_mfma(const unsigned short* __restrict__ qn,
                                                 const unsigned short* __restrict__ kn,
                                                 const float* __restrict__ log_temp,
                                                 float* __restrict__ xf,
                                                 float* __restrict__ out) {
    // per-wave C scratch: [160 n][16 m] with 20-float (80B) row stride (2-way conflicts only)
    __shared__ float clds[4][160 * 20];
    int wid = threadIdx.x >> 6, lane = threadIdx.x & 63;
    int tile = blockIdx.x * 4 + wid;
    int b = tile >> 10; int rem = tile & 1023; int y = rem >> 3; int x0 = (rem & 7) << 4;
    int l15 = lane & 15, quad = lane >> 4;

    // A-frag pointer: lane provides A[m=l15][k=quad*8+j]
    const s16x8* aptr = (const s16x8*)(qn + ((size_t)(b << 14) + y * Ww + x0 + l15) * Dd + quad * 8);
    // B-frag pointers: lane provides B[k=quad*8+j][n=l15] = k_nbr[p=f*16+l15][k]
    const s16x8* bptr[10];
#pragma unroll
    for (int f = 0; f < 10; f++) {
        int p = f * 16 + l15; if (p > 153) p = 153;
        int ry = p / 22, rx = p - ry * 22;
        int yy = min(max(y - 3 + ry, 0), Hh - 1);
        int xx = min(max(x0 - 3 + rx, 0), Ww - 1);
        bptr[f] = (const s16x8*)(kn + ((size_t)(b << 14) + yy * Ww + xx) * Dd + quad * 8);
    }
    f32x4 acc[10];
#pragma unroll
    for (int f = 0; f < 10; f++) acc[f] = (f32x4){0.f, 0.f, 0.f, 0.f};
#pragma unroll
    for (int k = 0; k < 8; k++) {       // K = 8 x 32 channels; 16B frag stride = 4 s16x8
        s16x8 a = aptr[k * 4];
#pragma unroll
        for (int f = 0; f < 10; f++) {
            s16x8 bb = bptr[f][k * 4];
            acc[f] = __builtin_amdgcn_mfma_f32_16x16x32_bf16(a, bb, acc[f], 0, 0, 0);
        }
    }
    // C/D layout: lane holds D[m = quad*4 + r][n = l15]  -> store as clds[n][m]
    float* cw = clds[wid];
#pragma unroll
    for (int f = 0; f < 10; f++) {
        int n = f * 16 + l15;
        *(f32x4*)(cw + n * 20 + quad * 4) = acc[f];
    }
    __syncthreads();

    // softmax epilogue: 4 lanes per pixel. pixel px = lane&15, part = lane>>4
    int px = l15, part = quad;
    int x = x0 + px;
    float inv_temp = expf(-log_temp[0]);   // 1/temp
    float vals[13];
    float vmax = -1e30f;
#pragma unroll
    for (int i = 0; i < 13; i++) {
        int s = part + 4 * i;
        if (s < 49) {
            int dy = s / 7 - 3, dx = s % 7 - 3;
            int ry = min(max(y + dy, 0), Hh - 1) - (y - 3);
            int rx = min(max(x + dx, 0), Ww - 1) - (x0 - 3);
            float v = cw[(ry * 22 + rx) * 20 + px];
            vals[i] = v;
            vmax = fmaxf(vmax, v);
        }
    }
    vmax = fmaxf(vmax, __shfl_xor(vmax, 16, 64));
    vmax = fmaxf(vmax, __shfl_xor(vmax, 32, 64));

    size_t pix = (size_t)(b << 14) + y * Ww + x;
    float* xp = xf + pix * 52;
    float se = 0.f, sey = 0.f, sex = 0.f, emax = 0.f;
#pragma unroll
    for (int i = 0; i < 13; i++) {
        int s = part + 4 * i;
        if (s < 49) {
            float e = expf((vals[i] - vmax) * inv_temp);
            se += e;
            sey += e * (float)(s / 7 - 3);
            sex += e * (float)(s % 7 - 3);
            emax = fmaxf(emax, e);
            xp[2 + s] = vals[i];
        }
    }
    se += __shfl_xor(se, 16, 64);  se += __shfl_xor(se, 32, 64);
    sey += __shfl_xor(sey, 16, 64); sey += __shfl_xor(sey, 32, 64);
    sex += __shfl_xor(sex, 16, 64); sex += __shfl_xor(sex, 32, 64);
    emax = fmaxf(emax, __shfl_xor(emax, 16, 64));
    emax = fmaxf(emax, __shfl_xor(emax, 32, 64));
    float inv_se = 1.0f / se;
    float dyv = sey * inv_se, dxv = sex * inv_se, conf = emax * inv_se;
    float* op = out + (size_t)b * 5 * HW + y * Ww + x;
    if (part == 0) { xp[0] = dyv;   op[2 * HW] = dyv; }
    if (part == 1) { xp[1] = dxv;   op[3 * HW] = dxv; }
    if (part == 2) { xp[51] = conf; op[4 * HW] = conf; }
}

// ---------- K0: transpose conv weights [OC,IC,5,5] -> [25,IC,OC] ----------
__global__ __launch_bounds__(256) void prep_weights(const float* __restrict__ w0,
                                                    const float* __restrict__ w1,
                                                    const float* __restrict__ w2,
                                                    float* __restrict__ t0,
                                                    float* __restrict__ t1,
                                                    float* __restrict__ t2) {
    int t = blockIdx.x * 256 + threadIdx.x;
    if (t < 41600) {                      // w0: 32x52x25
        int k = t / (52 * 32); int r = t % (52 * 32); int ic = r / 32, oc = r % 32;
        t0[t] = w0[oc * (52 * 25) + ic * 25 + k];
    } else if (t < 41600 + 25600) {       // w1: 32x32x25
        int u = t - 41600;
        int k = u / 1024; int r = u % 1024; int ic = r / 32, oc = r % 32;
        t1[u] = w1[oc * (32 * 25) + ic * 25 + k];
    } else if (t < 41600 + 25600 + 1600) {// w2: 2x32x25
        int u = t - 67200;
        int k = u / 64; int r = u % 64; int ic = r / 2, oc = r % 2;
        t2[u] = w2[oc * (32 * 25) + ic * 25 + k];
    }
}

__device__ __forceinline__ float gelu_exact(float v) {
    return 0.5f * v * (1.0f + erff(v * 0.70710678118654752f));
}

// ---------- conv 5x5 SAME (zero pad), channel-last in/out, fused GELU ----------
template <int IC, int OCTOT, int OCG, bool GELU>
__global__ __launch_bounds__(256) void conv5x5(const float* __restrict__ in,
                                               const float* __restrict__ wt,
                                               const float* __restrict__ bias,
                                               float* __restrict__ outp) {
    constexpr int NG = OCTOT / OCG;
    int x = blockIdx.x * 16 + threadIdx.x;
    int y = blockIdx.y * 16 + threadIdx.y;
    int b = blockIdx.z / NG;
    int g = blockIdx.z % NG;
    int ocb = g * OCG;
    float acc[OCG];
#pragma unroll
    for (int o = 0; o < OCG; o++) acc[o] = bias[ocb + o];
#pragma unroll
    for (int ky = 0; ky < 5; ky++) {
        int yy = y + ky - 2;
        if ((unsigned)yy >= (unsigned)Hh) continue;
#pragma unroll
        for (int kx = 0; kx < 5; kx++) {
            int xx = x + kx - 2;
            if ((unsigned)xx >= (unsigned)Ww) continue;
            const float* xp = in + (size_t)((b * Hh + yy) * Ww + xx) * IC;
            const float* wp = wt + (ky * 5 + kx) * IC * OCTOT + ocb;
#pragma unroll
            for (int ic4 = 0; ic4 < IC / 4; ic4++) {
                float4 xv = *(const float4*)(xp + ic4 * 4);
                const float* wq = wp + ic4 * 4 * OCTOT;
#pragma unroll
                for (int j = 0; j < 4; j++) {
                    float xs = (j == 0) ? xv.x : (j == 1) ? xv.y : (j == 2) ? xv.z : xv.w;
#pragma unroll
                    for (int o = 0; o < OCG; o++)
                        acc[o] = fmaf(xs, wq[j * OCTOT + o], acc[o]);
                }
            }
        }
    }
    float* op = outp + (size_t)((b * Hh + y) * Ww + x) * OCTOT + ocb;
#pragma unroll
    for (int o = 0; o < OCG; o++) {
        float v = acc[o];
        if (GELU) v = gelu_exact(v);
        op[o] = v;
    }
}

// ---------- conv2 (32->2) + residual add + sky scaling -> out ch0/ch1 ----------
__global__ __launch_bounds__(256) void conv5x5_final(const float* __restrict__ in,
                                                     const float* __restrict__ wt,
                                                     const float* __restrict__ bias,
                                                     const float* __restrict__ xf,
                                                     float* __restrict__ out) {
    int x = blockIdx.x * 16 + threadIdx.x;
    int y = blockIdx.y * 16 + threadIdx.y;
    int b = blockIdx.z;
    float a0 = bias[0], a1 = bias[1];
#pragma unroll
    for (int ky = 0; ky < 5; ky++) {
        int yy = y + ky - 2;
        if ((unsigned)yy >= (unsigned)Hh) continue;
#pragma unroll
        for (int kx = 0; kx < 5; kx++) {
            int xx = x + kx - 2;
            if ((unsigned)xx >= (unsigned)Ww) continue;
            const float* xp = in + (size_t)((b * Hh + yy) * Ww + xx) * 32;
            const float* wp = wt + (ky * 5 + kx) * 32 * 2;
#pragma unroll
            for (int ic4 = 0; ic4 < 8; ic4++) {
                float4 xv = *(const float4*)(xp + ic4 * 4);
#pragma unroll
                for (int j = 0; j < 4; j++) {
                    float xs = (j == 0) ? xv.x : (j == 1) ? xv.y : (j == 2) ? xv.z : xv.w;
                    a0 = fmaf(xs, wp[(ic4 * 4 + j) * 2 + 0], a0);
                    a1 = fmaf(xs, wp[(ic4 * 4 + j) * 2 + 1], a1);
                }
            }
        }
    }
    size_t pix = (size_t)((b * Hh + y) * Ww + x);
    float rdy = xf[pix * 52 + 0];
    float rdx = xf[pix * 52 + 1];
    float r0 = rdy + a0;   // refined dy
    float r1 = rdx + a1;   // refined dx
    float* op = out + (size_t)b * 5 * HW + y * Ww + x;
    op[0] = r1 * 1.6f;     // dra
    op[HW] = r0 * 1.6f;    // ddec
}

extern "C" void kernel_launch(void* const* d_in, const int* in_sizes, int n_in,
                              void* d_out, int out_size, void* d_ws, size_t ws_size,
                              hipStream_t stream) {
    const float* rub = (const float*)d_in[0];
    const float* vis = (const float*)d_in[1];
    const float* w0 = (const float*)d_in[2];
    const float* b0 = (const float*)d_in[3];
    const float* w1 = (const float*)d_in[4];
    const float* b1 = (const float*)d_in[5];
    const float* w2 = (const float*)d_in[6];
    const float* b2 = (const float*)d_in[7];
    const float* log_temp = (const float*)d_in[8];
    float* out = (float*)d_out;

    char* ws = (char*)d_ws;
    size_t off = 0;
    unsigned short* kn = (unsigned short*)(ws + off); off += (size_t)NPIX * Dd * 2;  // 33.5MB
    unsigned short* qn = (unsigned short*)(ws + off); off += (size_t)NPIX * Dd * 2;  // 33.5MB
    float* xf = (float*)(ws + off); off += (size_t)NPIX * 52 * 4;                    // 13.6MB
    float* h1 = (float*)(ws + off); off += (size_t)NPIX * 32 * 4;                    // 8.4MB
    float* h2 = (float*)(ws + off); off += (size_t)NPIX * 32 * 4;                    // 8.4MB
    float* t0 = (float*)(ws + off); off += 41600 * 4;
    float* t1 = (float*)(ws + off); off += 25600 * 4;
    float* t2 = (float*)(ws + off); off += 1600 * 4;

    prep_weights<<<(68800 + 255) / 256, 256, 0, stream>>>(w0, w1, w2, t0, t1, t2);
    norm_vis<<<NPIX / 4, 256, 0, stream>>>(vis, kn);
    interp_norm_q<<<NPIX / 4, 256, 0, stream>>>(rub, qn);
    corr_mfma<<<1024, 256, 0, stream>>>(qn, kn, log_temp, xf, out);

    dim3 blk(16, 16);
    conv5x5<52, 32, 16, true><<<dim3(8, 8, Bb * 2), blk, 0, stream>>>(xf, t0, b0, h1);
    conv5x5<32, 32, 16, true><<<dim3(8, 8, Bb * 2), blk, 0, stream>>>(h1, t1, b1, h2);
    conv5x5_final<<<dim3(8, 8, Bb), blk, 0, stream>>>(h2, t2, b2, xf, out);
}

// Round 3
// 304.108 us; speedup vs baseline: 2.0676x; 1.4169x over previous
//
#include <hip/hip_runtime.h>
#include <math.h>

#define Hh 128
#define Ww 128
#define Dd 256
#define Bb 4
#define HW (Hh*Ww)        // 16384
#define NPIX (Bb*HW)      // 65536

typedef __attribute__((ext_vector_type(8))) short s16x8;   // 8 bf16 (4 VGPRs)
typedef __attribute__((ext_vector_type(4))) float f32x4;

// ---------- wave (64-lane) butterfly reductions ----------
__device__ __forceinline__ float wsum(float v) {
#pragma unroll
    for (int o = 32; o; o >>= 1) v += __shfl_xor(v, o, 64);
    return v;
}

// fp32 -> bf16 RNE
__device__ __forceinline__ unsigned short f2bf(float f) {
    unsigned u = __float_as_uint(f);
    u += 0x7FFF + ((u >> 16) & 1);
    return (unsigned short)(u >> 16);
}

__device__ __forceinline__ float gelu_exact(float v) {
    return 0.5f * v * (1.0f + erff(v * 0.70710678118654752f));
}

// ---------- K1: L2-normalize vis tokens -> kn [B,H,W,D] bf16 ----------
__global__ __launch_bounds__(256) void norm_vis(const float* __restrict__ vis,
                                                unsigned short* __restrict__ kn) {
    int wid = threadIdx.x >> 6, lane = threadIdx.x & 63;
    int pix = blockIdx.x * 4 + wid;
    const float4 v = *(const float4*)(vis + (size_t)pix * Dd + lane * 4);
    float ss = wsum(v.x * v.x + v.y * v.y + v.z * v.z + v.w * v.w);
    float inv = 1.0f / fmaxf(sqrtf(ss), 1e-12f);
    ushort4 o;
    o.x = f2bf(v.x * inv); o.y = f2bf(v.y * inv);
    o.z = f2bf(v.z * inv); o.w = f2bf(v.w * inv);
    *(ushort4*)(kn + (size_t)pix * Dd + lane * 4) = o;
}

// ---------- K2: bilinear-upsample rubin 64x64 -> 128x128 + L2 norm -> qn bf16 ----------
__global__ __launch_bounds__(256) void interp_norm_q(const float* __restrict__ rub,
                                                     unsigned short* __restrict__ qn) {
    int wid = threadIdx.x >> 6, lane = threadIdx.x & 63;
    int pix = blockIdx.x * 4 + wid;
    int b = pix >> 14; int yx = pix & 16383; int y = yx >> 7; int x = yx & 127;
    float sy = 0.5f * y - 0.25f;
    float sx = 0.5f * x - 0.25f;
    int y0 = (int)floorf(sy); float fy = sy - (float)y0;
    int x0 = (int)floorf(sx); float fx = sx - (float)x0;
    int y0c = max(y0, 0), y1c = min(y0 + 1, 63);
    int x0c = max(x0, 0), x1c = min(x0 + 1, 63);
    const float* base = rub + (size_t)b * 4096 * Dd;
    const float4 v00 = *(const float4*)(base + (size_t)(y0c * 64 + x0c) * Dd + lane * 4);
    const float4 v01 = *(const float4*)(base + (size_t)(y0c * 64 + x1c) * Dd + lane * 4);
    const float4 v10 = *(const float4*)(base + (size_t)(y1c * 64 + x0c) * Dd + lane * 4);
    const float4 v11 = *(const float4*)(base + (size_t)(y1c * 64 + x1c) * Dd + lane * 4);
    float w00 = (1.f - fy) * (1.f - fx), w01 = (1.f - fy) * fx;
    float w10 = fy * (1.f - fx), w11 = fy * fx;
    float4 v;
    v.x = w00 * v00.x + w01 * v01.x + w10 * v10.x + w11 * v11.x;
    v.y = w00 * v00.y + w01 * v01.y + w10 * v10.y + w11 * v11.y;
    v.z = w00 * v00.z + w01 * v01.z + w10 * v10.z + w11 * v11.z;
    v.w = w00 * v00.w + w01 * v01.w + w10 * v10.w + w11 * v11.w;
    float ss = wsum(v.x * v.x + v.y * v.y + v.z * v.z + v.w * v.w);
    float inv = 1.0f / fmaxf(sqrtf(ss), 1e-12f);
    ushort4 o;
    o.x = f2bf(v.x * inv); o.y = f2bf(v.y * inv);
    o.z = f2bf(v.z * inv); o.w = f2bf(v.w * inv);
    *(ushort4*)(qn + (size_t)pix * Dd + lane * 4) = o;
}

// ---------- K3: MFMA corr (16 px row-tile x 154 neighborhood) + softmax ----------
// writes xb [B,H,W,64] bf16 (ch0=dy, ch1=dx, ch2..50=corr, ch51=conf, ch52..63=0)
// writes out channels 2(dy),3(dx),4(conf) fp32
__global__ __launch_bounds__(256) void corr_mfma(const unsigned short* __restrict__ qn,
                                                 const unsigned short* __restrict__ kn,
                                                 const float* __restrict__ log_temp,
                                                 unsigned short* __restrict__ xb,
                                                 float* __restrict__ out) {
    // per-wave C scratch: [160 n][16 m] with 20-float (80B) row stride (2-way conflicts only)
    __shared__ float clds[4][160 * 20];
    int wid = threadIdx.x >> 6, lane = threadIdx.x & 63;
    int tile = blockIdx.x * 4 + wid;
    int b = tile >> 10; int rem = tile & 1023; int y = rem >> 3; int x0 = (rem & 7) << 4;
    int l15 = lane & 15, quad = lane >> 4;

    const s16x8* aptr = (const s16x8*)(qn + ((size_t)(b << 14) + y * Ww + x0 + l15) * Dd + quad * 8);
    const s16x8* bptr[10];
#pragma unroll
    for (int f = 0; f < 10; f++) {
        int p = f * 16 + l15; if (p > 153) p = 153;
        int ry = p / 22, rx = p - ry * 22;
        int yy = min(max(y - 3 + ry, 0), Hh - 1);
        int xx = min(max(x0 - 3 + rx, 0), Ww - 1);
        bptr[f] = (const s16x8*)(kn + ((size_t)(b << 14) + yy * Ww + xx) * Dd + quad * 8);
    }
    f32x4 acc[10];
#pragma unroll
    for (int f = 0; f < 10; f++) acc[f] = (f32x4){0.f, 0.f, 0.f, 0.f};
#pragma unroll
    for (int k = 0; k < 8; k++) {
        s16x8 a = aptr[k * 4];
#pragma unroll
        for (int f = 0; f < 10; f++) {
            s16x8 bb = bptr[f][k * 4];
            acc[f] = __builtin_amdgcn_mfma_f32_16x16x32_bf16(a, bb, acc[f], 0, 0, 0);
        }
    }
    float* cw = clds[wid];
#pragma unroll
    for (int f = 0; f < 10; f++) {
        int n = f * 16 + l15;
        *(f32x4*)(cw + n * 20 + quad * 4) = acc[f];
    }
    __syncthreads();

    // softmax epilogue: 4 lanes per pixel. pixel px = lane&15, part = lane>>4
    int px = l15, part = quad;
    int x = x0 + px;
    float inv_temp = expf(-log_temp[0]);   // 1/temp
    float vals[13];
    float vmax = -1e30f;
#pragma unroll
    for (int i = 0; i < 13; i++) {
        int s = part + 4 * i;
        if (s < 49) {
            int dy = s / 7 - 3, dx = s % 7 - 3;
            int ry = min(max(y + dy, 0), Hh - 1) - (y - 3);
            int rx = min(max(x + dx, 0), Ww - 1) - (x0 - 3);
            float v = cw[(ry * 22 + rx) * 20 + px];
            vals[i] = v;
            vmax = fmaxf(vmax, v);
        }
    }
    vmax = fmaxf(vmax, __shfl_xor(vmax, 16, 64));
    vmax = fmaxf(vmax, __shfl_xor(vmax, 32, 64));

    size_t pix = (size_t)(b << 14) + y * Ww + x;
    unsigned short* xp = xb + pix * 64;
    float se = 0.f, sey = 0.f, sex = 0.f, emax = 0.f;
#pragma unroll
    for (int i = 0; i < 13; i++) {
        int s = part + 4 * i;
        if (s < 49) {
            float e = expf((vals[i] - vmax) * inv_temp);
            se += e;
            sey += e * (float)(s / 7 - 3);
            sex += e * (float)(s % 7 - 3);
            emax = fmaxf(emax, e);
            xp[2 + s] = f2bf(vals[i]);
        }
    }
    se += __shfl_xor(se, 16, 64);  se += __shfl_xor(se, 32, 64);
    sey += __shfl_xor(sey, 16, 64); sey += __shfl_xor(sey, 32, 64);
    sex += __shfl_xor(sex, 16, 64); sex += __shfl_xor(sex, 32, 64);
    emax = fmaxf(emax, __shfl_xor(emax, 16, 64));
    emax = fmaxf(emax, __shfl_xor(emax, 32, 64));
    float inv_se = 1.0f / se;
    float dyv = sey * inv_se, dxv = sex * inv_se, conf = emax * inv_se;
    float* op = out + (size_t)b * 5 * HW + y * Ww + x;
    if (part == 0) { xp[0] = f2bf(dyv);   op[2 * HW] = dyv; }
    if (part == 1) { xp[1] = f2bf(dxv);   op[3 * HW] = dxv; }
    if (part == 2) { xp[51] = f2bf(conf); op[4 * HW] = conf; }
    if (part == 3) {
        ushort4 z = {0, 0, 0, 0};
        *(ushort4*)(xp + 52) = z;
        *(ushort4*)(xp + 56) = z;
        *(ushort4*)(xp + 60) = z;
    }
}

// ---------- K0: conv weights -> bf16 [tap][n][k] (IC zero-padded, OC2 padded to 16) ----------
// wb0: 25 x 32 x 64 (k<52 real), wb1: 25 x 32 x 32, wb2: 25 x 16 x 32 (n<2 real)
__global__ __launch_bounds__(256) void prep_weights(const float* __restrict__ w0,
                                                    const float* __restrict__ w1,
                                                    const float* __restrict__ w2,
                                                    unsigned short* __restrict__ wb0,
                                                    unsigned short* __restrict__ wb1,
                                                    unsigned short* __restrict__ wb2) {
    int t = blockIdx.x * 256 + threadIdx.x;
    if (t < 51200) {
        int tap = t >> 11; int r = t & 2047; int n = r >> 6; int k = r & 63;
        wb0[t] = (k < 52) ? f2bf(w0[n * 1300 + k * 25 + tap]) : (unsigned short)0;
    } else if (t < 76800) {
        int u = t - 51200; int tap = u >> 10; int r = u & 1023; int n = r >> 5; int k = r & 31;
        wb1[u] = f2bf(w1[n * 800 + k * 25 + tap]);
    } else if (t < 89600) {
        int u = t - 76800; int tap = u >> 9; int r = u & 511; int n = r >> 5; int k = r & 31;
        wb2[u] = (n < 2) ? f2bf(w2[n * 800 + k * 25 + tap]) : (unsigned short)0;
    }
}

// ---------- MFMA implicit-GEMM 5x5 conv, channel-last bf16, fp32 acc ----------
// wave per 16-pixel row tile; C[m=pixel][n=oc]; zero-pad SAME via per-lane A zeroing
template <int KSTEPS, int NF, bool GELU>
__global__ __launch_bounds__(256) void conv_mfma(const unsigned short* __restrict__ in,
                                                 const unsigned short* __restrict__ wb,
                                                 const float* __restrict__ bias,
                                                 unsigned short* __restrict__ outp) {
    constexpr int ICP = KSTEPS * 32;
    constexpr int OC = NF * 16;
    int wid = threadIdx.x >> 6, lane = threadIdx.x & 63;
    int tile = blockIdx.x * 4 + wid;
    int b = tile >> 10, rem = tile & 1023, y = rem >> 3, x0 = (rem & 7) << 4;
    int l15 = lane & 15, quad = lane >> 4;
    const s16x8 zero = {0, 0, 0, 0, 0, 0, 0, 0};
    f32x4 acc[NF];
#pragma unroll
    for (int g = 0; g < NF; g++) acc[g] = (f32x4){0.f, 0.f, 0.f, 0.f};
#pragma unroll
    for (int ky = 0; ky < 5; ky++) {
        int yy = y + ky - 2;
        if ((unsigned)yy >= (unsigned)Hh) continue;
        const unsigned short* rowp = in + ((size_t)(b << 14) + yy * Ww) * ICP;
#pragma unroll
        for (int kx = 0; kx < 5; kx++) {
            int xc = x0 + l15 + kx - 2;
            bool valid = (unsigned)xc < (unsigned)Ww;
            const s16x8* ap = (const s16x8*)(rowp + (ptrdiff_t)xc * ICP + quad * 8);
            const unsigned short* wtap = wb + (ky * 5 + kx) * (OC * ICP);
#pragma unroll
            for (int ks = 0; ks < KSTEPS; ks++) {
                s16x8 a = valid ? ap[ks * 4] : zero;
#pragma unroll
                for (int g = 0; g < NF; g++) {
                    s16x8 bb = *(const s16x8*)(wtap + (g * 16 + l15) * ICP + ks * 32 + quad * 8);
                    acc[g] = __builtin_amdgcn_mfma_f32_16x16x32_bf16(a, bb, acc[g], 0, 0, 0);
                }
            }
        }
    }
    size_t pixbase = (size_t)(b << 14) + y * Ww + x0;
#pragma unroll
    for (int g = 0; g < NF; g++) {
        float bv = bias[g * 16 + l15];
#pragma unroll
        for (int r = 0; r < 4; r++) {
            int m = quad * 4 + r;
            float v = acc[g][r] + bv;
            if (GELU) v = gelu_exact(v);
            outp[(pixbase + m) * OC + g * 16 + l15] = f2bf(v);
        }
    }
}

// ---------- final conv (32->2) MFMA + residual + sky scaling ----------
__global__ __launch_bounds__(256) void conv_final_mfma(const unsigned short* __restrict__ in,
                                                       const unsigned short* __restrict__ wb,
                                                       const float* __restrict__ bias,
                                                       float* __restrict__ out) {
    __shared__ float cl[4][16][2];
    int wid = threadIdx.x >> 6, lane = threadIdx.x & 63;
    int tile = blockIdx.x * 4 + wid;
    int b = tile >> 10, rem = tile & 1023, y = rem >> 3, x0 = (rem & 7) << 4;
    int l15 = lane & 15, quad = lane >> 4;
    const s16x8 zero = {0, 0, 0, 0, 0, 0, 0, 0};
    f32x4 acc = (f32x4){0.f, 0.f, 0.f, 0.f};
#pragma unroll
    for (int ky = 0; ky < 5; ky++) {
        int yy = y + ky - 2;
        if ((unsigned)yy >= (unsigned)Hh) continue;
        const unsigned short* rowp = in + ((size_t)(b << 14) + yy * Ww) * 32;
#pragma unroll
        for (int kx = 0; kx < 5; kx++) {
            int xc = x0 + l15 + kx - 2;
            bool valid = (unsigned)xc < (unsigned)Ww;
            const s16x8* ap = (const s16x8*)(rowp + (ptrdiff_t)xc * 32 + quad * 8);
            s16x8 a = valid ? ap[0] : zero;
            s16x8 bb = *(const s16x8*)(wb + (ky * 5 + kx) * 512 + l15 * 32 + quad * 8);
            acc = __builtin_amdgcn_mfma_f32_16x16x32_bf16(a, bb, acc, 0, 0, 0);
        }
    }
    if (l15 < 2) {
        float bv = bias[l15];
#pragma unroll
        for (int r = 0; r < 4; r++) cl[wid][quad * 4 + r][l15] = acc[r] + bv;
    }
    __syncthreads();
    if (quad == 0) {
        size_t p5 = (size_t)b * 5 * HW + y * Ww + x0 + l15;
        float a0 = cl[wid][l15][0], a1 = cl[wid][l15][1];
        float dy = out[p5 + 2 * HW], dx = out[p5 + 3 * HW];
        out[p5] = (dx + a1) * 1.6f;        // dra
        out[p5 + HW] = (dy + a0) * 1.6f;   // ddec
    }
}

extern "C" void kernel_launch(void* const* d_in, const int* in_sizes, int n_in,
                              void* d_out, int out_size, void* d_ws, size_t ws_size,
                              hipStream_t stream) {
    const float* rub = (const float*)d_in[0];
    const float* vis = (const float*)d_in[1];
    const float* w0 = (const float*)d_in[2];
    const float* b0 = (const float*)d_in[3];
    const float* w1 = (const float*)d_in[4];
    const float* b1 = (const float*)d_in[5];
    const float* w2 = (const float*)d_in[6];
    const float* b2 = (const float*)d_in[7];
    const float* log_temp = (const float*)d_in[8];
    float* out = (float*)d_out;

    char* ws = (char*)d_ws;
    size_t off = 0;
    unsigned short* kn = (unsigned short*)(ws + off); off += (size_t)NPIX * Dd * 2;  // 33.5MB
    unsigned short* qn = (unsigned short*)(ws + off); off += (size_t)NPIX * Dd * 2;  // 33.5MB
    unsigned short* xb = (unsigned short*)(ws + off); off += (size_t)NPIX * 64 * 2;  // 8.4MB
    unsigned short* h1 = (unsigned short*)(ws + off); off += (size_t)NPIX * 32 * 2;  // 4.2MB
    unsigned short* h2 = (unsigned short*)(ws + off); off += (size_t)NPIX * 32 * 2;  // 4.2MB
    unsigned short* wb0 = (unsigned short*)(ws + off); off += 51200 * 2;
    unsigned short* wb1 = (unsigned short*)(ws + off); off += 25600 * 2;
    unsigned short* wb2 = (unsigned short*)(ws + off); off += 12800 * 2;

    prep_weights<<<350, 256, 0, stream>>>(w0, w1, w2, wb0, wb1, wb2);
    norm_vis<<<NPIX / 4, 256, 0, stream>>>(vis, kn);
    interp_norm_q<<<NPIX / 4, 256, 0, stream>>>(rub, qn);
    corr_mfma<<<1024, 256, 0, stream>>>(qn, kn, log_temp, xb, out);
    conv_mfma<2, 2, true><<<1024, 256, 0, stream>>>(xb, wb0, b0, h1);
    conv_mfma<1, 2, true><<<1024, 256, 0, stream>>>(h1, wb1, b1, h2);
    conv_final_mfma<<<1024, 256, 0, stream>>>(h2, wb2, b2, out);
}